// Round 1
// baseline (224.832 us; speedup 1.0000x reference)
//
#include <hip/hip_runtime.h>
#include <hip/hip_bf16.h>

#define NUM_SEGMENTS 50000

// One block per segment. Index is sorted, so segment s occupies the
// contiguous row range [lower_bound(s), lower_bound(s+1)).
// Thread t owns output column t; rows are read fully coalesced
// (128 threads x 4B = 512B contiguous per row).
__global__ void __launch_bounds__(128)
seg_weighted_avg(const float* __restrict__ prop,
                 const float* __restrict__ w,
                 const int*   __restrict__ idx,
                 float*       __restrict__ out,
                 int n, int d) {
    const int s = blockIdx.x;

    // lower_bound(idx, s): first i with idx[i] >= s
    int lo = 0, hi = n;
    while (lo < hi) {
        int mid = (lo + hi) >> 1;
        if (idx[mid] < s) lo = mid + 1; else hi = mid;
    }
    const int start = lo;
    // upper_bound(idx, s): first i with idx[i] > s
    hi = n;
    while (lo < hi) {
        int mid = (lo + hi) >> 1;
        if (idx[mid] <= s) lo = mid + 1; else hi = mid;
    }
    const int end = lo;

    const int t = threadIdx.x;
    float acc  = 0.0f;
    float wsum = 0.0f;
    for (int i = start; i < end; ++i) {
        const float wi = w[i];             // broadcast (same addr all lanes)
        wsum += wi;
        acc  += wi * prop[(size_t)i * d + t];
    }
    // 0/0 -> NaN for empty segments, matching the JAX reference.
    out[(size_t)s * d + t] = acc / wsum;
}

extern "C" void kernel_launch(void* const* d_in, const int* in_sizes, int n_in,
                              void* d_out, int out_size, void* d_ws, size_t ws_size,
                              hipStream_t stream) {
    const float* prop = (const float*)d_in[0];
    const float* w    = (const float*)d_in[1];
    const int*   idx  = (const int*)d_in[2];
    float* out        = (float*)d_out;

    const int n = in_sizes[1];              // 1,000,000
    const int d = in_sizes[0] / in_sizes[1]; // 128

    seg_weighted_avg<<<NUM_SEGMENTS, 128, 0, stream>>>(prop, w, idx, out, n, d);
}

// Round 2
// 106.835 us; speedup vs baseline: 2.1045x; 2.1045x over previous
//
#include <hip/hip_runtime.h>
#include <hip/hip_bf16.h>

#define NUM_SEGMENTS 50000

// Prepass: starts[s] = lower_bound(idx, s) for s in [0, S]; starts[S] = n.
// idx is sorted, so boundaries are where idx[i] != idx[i-1].
// Every starts[] entry is written exactly once per call (deterministic,
// no reliance on ws state across calls).
__global__ void build_starts(const int* __restrict__ idx,
                             int* __restrict__ starts,
                             int n, int S) {
    int i = blockIdx.x * blockDim.x + threadIdx.x;
    if (i >= n) return;
    int cur = idx[i];
    if (i == 0) {
        for (int s = 0; s <= cur; ++s) starts[s] = 0;
    } else {
        int prev = idx[i - 1];
        for (int s = prev + 1; s <= cur; ++s) starts[s] = i;
    }
    if (i == n - 1) {
        for (int s = cur + 1; s <= S; ++s) starts[s] = n;
    }
}

// One block per segment; thread t owns output column t.
// Rows are contiguous [starts[s], starts[s+1]). Unroll-by-4 with explicit
// preloads keeps 4 row-loads (+4 broadcast w-loads) in flight per wave.
__global__ void __launch_bounds__(128)
seg_weighted_avg(const float* __restrict__ prop,
                 const float* __restrict__ w,
                 const int*   __restrict__ starts,
                 float*       __restrict__ out,
                 int d) {
    const int s     = blockIdx.x;
    const int start = starts[s];
    const int end   = starts[s + 1];
    const int t     = threadIdx.x;

    const float* p = prop + (size_t)start * d + t;
    float acc  = 0.0f;
    float wsum = 0.0f;

    int i = start;
    const int d2 = d * 2, d3 = d * 3, d4 = d * 4;
    for (; i + 4 <= end; i += 4) {
        float w0 = w[i], w1 = w[i + 1], w2 = w[i + 2], w3 = w[i + 3];
        float p0 = p[0], p1 = p[d], p2 = p[d2], p3 = p[d3];
        p += d4;
        acc  = fmaf(w0, p0, acc);
        acc  = fmaf(w1, p1, acc);
        acc  = fmaf(w2, p2, acc);
        acc  = fmaf(w3, p3, acc);
        wsum += (w0 + w1) + (w2 + w3);
    }
    for (; i < end; ++i) {
        float wi = w[i];
        wsum += wi;
        acc  = fmaf(wi, p[0], acc);
        p += d;
    }

    // 0/0 -> NaN for empty segments, matching the JAX reference.
    out[(size_t)s * d + t] = acc / wsum;
}

extern "C" void kernel_launch(void* const* d_in, const int* in_sizes, int n_in,
                              void* d_out, int out_size, void* d_ws, size_t ws_size,
                              hipStream_t stream) {
    const float* prop = (const float*)d_in[0];
    const float* w    = (const float*)d_in[1];
    const int*   idx  = (const int*)d_in[2];
    float* out        = (float*)d_out;

    const int n = in_sizes[1];                // 1,000,000
    const int d = in_sizes[0] / in_sizes[1];  // 128
    const int S = NUM_SEGMENTS;

    int* starts = (int*)d_ws;                 // (S+1) ints = ~200 KB << ws_size

    build_starts<<<(n + 255) / 256, 256, 0, stream>>>(idx, starts, n, S);
    seg_weighted_avg<<<S, d, 0, stream>>>(prop, w, starts, out, d);
}

// Round 3
// 106.462 us; speedup vs baseline: 2.1119x; 1.0035x over previous
//
#include <hip/hip_runtime.h>
#include <hip/hip_bf16.h>

#define NUM_SEGMENTS 50000

// Prepass: starts[s] = lower_bound(idx, s) for s in [0, S]; starts[S] = n.
// idx is sorted, so boundaries are where idx[i] != idx[i-1].
// Every starts[] entry is written exactly once per call (deterministic).
__global__ void build_starts(const int* __restrict__ idx,
                             int* __restrict__ starts,
                             int n, int S) {
    int i = blockIdx.x * blockDim.x + threadIdx.x;
    if (i >= n) return;
    int cur = idx[i];
    if (i == 0) {
        for (int s = 0; s <= cur; ++s) starts[s] = 0;
    } else {
        int prev = idx[i - 1];
        for (int s = prev + 1; s <= cur; ++s) starts[s] = i;
    }
    if (i == n - 1) {
        for (int s = cur + 1; s <= S; ++s) starts[s] = n;
    }
}

// Specialized d=128. One block (128 thr) per segment.
// Thread t: float4-column (t&31), row-group (t>>5). 4 row groups stride the
// segment's rows by 4; unroll x2 keeps 2 float4 loads (32B/lane) in flight.
// Epilogue: LDS-reduce the 4 groups, 32 lanes store the 512B output row.
__global__ void __launch_bounds__(128)
seg_weighted_avg_d128(const float4* __restrict__ prop4,
                      const float*  __restrict__ w,
                      const int*    __restrict__ starts,
                      float4*       __restrict__ out4) {
    const int s     = blockIdx.x;
    const int start = starts[s];
    const int nrows = starts[s + 1] - start;

    const int t    = threadIdx.x;
    const int col4 = t & 31;   // which float4 within the row (0..31)
    const int rg   = t >> 5;   // row group (0..3)

    const float4* p = prop4 + (size_t)(start + rg) * 32 + col4;
    const float*  wp = w + start;

    float4 acc = make_float4(0.f, 0.f, 0.f, 0.f);
    float wsum = 0.0f;

    int r = rg;
    for (; r + 4 < nrows; r += 8) {           // rows r and r+4 both valid
        float  w0 = wp[r],        w1 = wp[r + 4];
        float4 p0 = p[0],         p1 = p[128]; // +4 rows = +128 float4
        p += 256;                              // +8 rows
        acc.x = fmaf(w0, p0.x, acc.x); acc.y = fmaf(w0, p0.y, acc.y);
        acc.z = fmaf(w0, p0.z, acc.z); acc.w = fmaf(w0, p0.w, acc.w);
        acc.x = fmaf(w1, p1.x, acc.x); acc.y = fmaf(w1, p1.y, acc.y);
        acc.z = fmaf(w1, p1.z, acc.z); acc.w = fmaf(w1, p1.w, acc.w);
        wsum += w0 + w1;
    }
    for (; r < nrows; r += 4) {               // remainder, one row per step
        float  w0 = wp[r];
        float4 p0 = p[0];
        p += 128;
        acc.x = fmaf(w0, p0.x, acc.x); acc.y = fmaf(w0, p0.y, acc.y);
        acc.z = fmaf(w0, p0.z, acc.z); acc.w = fmaf(w0, p0.w, acc.w);
        wsum += w0;
    }

    __shared__ float4 lacc[128];
    __shared__ float  lw[128];
    lacc[t] = acc;
    lw[t]   = wsum;
    __syncthreads();

    if (t < 32) {
        float4 a0 = lacc[t], a1 = lacc[t + 32], a2 = lacc[t + 64], a3 = lacc[t + 96];
        // lanes within a group hold identical wsum; sum one lane per group
        float ws = (lw[t] + lw[t + 32]) + (lw[t + 64] + lw[t + 96]);
        float4 res;
        res.x = ((a0.x + a1.x) + (a2.x + a3.x)) / ws;
        res.y = ((a0.y + a1.y) + (a2.y + a3.y)) / ws;
        res.z = ((a0.z + a1.z) + (a2.z + a3.z)) / ws;
        res.w = ((a0.w + a1.w) + (a2.w + a3.w)) / ws;
        out4[(size_t)s * 32 + t] = res;       // 0/0 -> NaN for empty segments
    }
}

// Generic fallback (d != 128): round-1 kernel.
__global__ void __launch_bounds__(128)
seg_weighted_avg_generic(const float* __restrict__ prop,
                         const float* __restrict__ w,
                         const int*   __restrict__ starts,
                         float*       __restrict__ out,
                         int d) {
    const int s     = blockIdx.x;
    const int start = starts[s];
    const int end   = starts[s + 1];
    const int t     = threadIdx.x;
    const float* p  = prop + (size_t)start * d + t;
    float acc = 0.f, wsum = 0.f;
    for (int i = start; i < end; ++i) {
        float wi = w[i];
        wsum += wi;
        acc = fmaf(wi, p[0], acc);
        p += d;
    }
    out[(size_t)s * d + t] = acc / wsum;
}

extern "C" void kernel_launch(void* const* d_in, const int* in_sizes, int n_in,
                              void* d_out, int out_size, void* d_ws, size_t ws_size,
                              hipStream_t stream) {
    const float* prop = (const float*)d_in[0];
    const float* w    = (const float*)d_in[1];
    const int*   idx  = (const int*)d_in[2];
    float* out        = (float*)d_out;

    const int n = in_sizes[1];                // 1,000,000
    const int d = in_sizes[0] / in_sizes[1];  // 128
    const int S = NUM_SEGMENTS;

    int* starts = (int*)d_ws;                 // (S+1) ints << ws_size

    build_starts<<<(n + 255) / 256, 256, 0, stream>>>(idx, starts, n, S);

    if (d == 128) {
        seg_weighted_avg_d128<<<S, 128, 0, stream>>>(
            (const float4*)prop, w, starts, (float4*)out);
    } else {
        seg_weighted_avg_generic<<<S, d, 0, stream>>>(prop, w, starts, out, d);
    }
}

// Round 4
// 96.528 us; speedup vs baseline: 2.3292x; 1.1029x over previous
//
#include <hip/hip_runtime.h>
#include <hip/hip_bf16.h>

#define NUM_SEGMENTS 50000

typedef float f32x4 __attribute__((ext_vector_type(4)));

__device__ __forceinline__ f32x4 ntload4(const f32x4* p) {
    return __builtin_nontemporal_load(p);
}
__device__ __forceinline__ void ntstore4(f32x4* p, f32x4 v) {
    __builtin_nontemporal_store(v, p);
}

// Prepass: starts[s] = lower_bound(idx, s); starts[S] = n.
// int4-vectorized: 250K threads, one int4 load + one scalar neighbor load.
__global__ void build_starts_v4(const int4* __restrict__ idx4,
                                const int*  __restrict__ idx,
                                int* __restrict__ starts,
                                int n4, int n, int S) {
    int i4 = blockIdx.x * blockDim.x + threadIdx.x;
    if (i4 >= n4) return;
    int4 v = idx4[i4];
    int base = i4 * 4;
    int prev = (base == 0) ? -1 : idx[base - 1];
    int a0 = v.x, a1 = v.y, a2 = v.z, a3 = v.w;
    for (int s = prev + 1; s <= a0; ++s) starts[s] = base;
    for (int s = a0 + 1;  s <= a1; ++s) starts[s] = base + 1;
    for (int s = a1 + 1;  s <= a2; ++s) starts[s] = base + 2;
    for (int s = a2 + 1;  s <= a3; ++s) starts[s] = base + 3;
    if (base + 4 >= n) {
        for (int s = a3 + 1; s <= S; ++s) starts[s] = n;
    }
}

// Tail for n not divisible by 4 (no-op for the expected n=1M).
__global__ void build_starts_tail(const int* __restrict__ idx,
                                  int* __restrict__ starts,
                                  int n4, int n, int S) {
    int i = n4 * 4 + blockIdx.x * blockDim.x + threadIdx.x;
    if (i >= n) return;
    int cur = idx[i];
    int prev = (i == 0) ? -1 : idx[i - 1];
    for (int s = prev + 1; s <= cur; ++s) starts[s] = i;
    if (i == n - 1)
        for (int s = cur + 1; s <= S; ++s) starts[s] = n;
}

// Accumulate one segment's rows for this thread (col4, row-group rg).
__device__ __forceinline__ void accum_seg(const f32x4* __restrict__ prop4,
                                          const float* __restrict__ w,
                                          int start, int nrows,
                                          int col4, int rg,
                                          f32x4& acc, float& wsum) {
    const f32x4* p  = prop4 + (size_t)(start + rg) * 32 + col4;
    const float* wp = w + start;
    int r = rg;
    for (; r + 4 < nrows; r += 8) {
        float w0 = wp[r], w1 = wp[r + 4];
        f32x4 p0 = ntload4(p), p1 = ntload4(p + 128);
        p += 256;
        acc += p0 * w0;
        acc += p1 * w1;
        wsum += w0 + w1;
    }
    for (; r < nrows; r += 4) {
        float w0 = wp[r];
        f32x4 p0 = ntload4(p);
        p += 128;
        acc += p0 * w0;
        wsum += w0;
    }
}

// Specialized d=128. One block (128 thr) per TWO consecutive segments.
// Thread t: float4-column (t&31), row-group (t>>5).
__global__ void __launch_bounds__(128)
seg_weighted_avg_d128(const f32x4* __restrict__ prop4,
                      const float* __restrict__ w,
                      const int*   __restrict__ starts,
                      f32x4*       __restrict__ out4) {
    const int s0  = blockIdx.x * 2;
    const int st0 = starts[s0];
    const int st1 = starts[s0 + 1];
    const int st2 = starts[s0 + 2];

    const int t    = threadIdx.x;
    const int col4 = t & 31;
    const int rg   = t >> 5;

    f32x4 accA = (f32x4)0.f, accB = (f32x4)0.f;
    float wsA = 0.f, wsB = 0.f;

    accum_seg(prop4, w, st0, st1 - st0, col4, rg, accA, wsA);
    accum_seg(prop4, w, st1, st2 - st1, col4, rg, accB, wsB);

    __shared__ f32x4 laccA[128], laccB[128];
    __shared__ float lwA[128], lwB[128];
    laccA[t] = accA; laccB[t] = accB;
    lwA[t]   = wsA;  lwB[t]   = wsB;
    __syncthreads();

    if (t < 64) {
        const f32x4* lacc = (t < 32) ? laccA : laccB;
        const float* lw   = (t < 32) ? lwA   : lwB;
        const int u = t & 31;
        f32x4 a = (lacc[u] + lacc[u + 32]) + (lacc[u + 64] + lacc[u + 96]);
        float ws = (lw[u] + lw[u + 32]) + (lw[u + 64] + lw[u + 96]);
        // 0/0 -> NaN for empty segments, matching the JAX reference.
        ntstore4((f32x4*)&out4[(size_t)(s0 + (t >> 5)) * 32 + u], a / ws);
    }
}

// Generic fallback (d != 128).
__global__ void __launch_bounds__(128)
seg_weighted_avg_generic(const float* __restrict__ prop,
                         const float* __restrict__ w,
                         const int*   __restrict__ starts,
                         float*       __restrict__ out,
                         int d) {
    const int s     = blockIdx.x;
    const int start = starts[s];
    const int end   = starts[s + 1];
    const int t     = threadIdx.x;
    const float* p  = prop + (size_t)start * d + t;
    float acc = 0.f, wsum = 0.f;
    for (int i = start; i < end; ++i) {
        float wi = w[i];
        wsum += wi;
        acc = fmaf(wi, p[0], acc);
        p += d;
    }
    out[(size_t)s * d + t] = acc / wsum;
}

extern "C" void kernel_launch(void* const* d_in, const int* in_sizes, int n_in,
                              void* d_out, int out_size, void* d_ws, size_t ws_size,
                              hipStream_t stream) {
    const float* prop = (const float*)d_in[0];
    const float* w    = (const float*)d_in[1];
    const int*   idx  = (const int*)d_in[2];
    float* out        = (float*)d_out;

    const int n = in_sizes[1];                // 1,000,000
    const int d = in_sizes[0] / in_sizes[1];  // 128
    const int S = NUM_SEGMENTS;

    int* starts = (int*)d_ws;                 // (S+1) ints << ws_size

    const int n4 = n / 4;
    build_starts_v4<<<(n4 + 255) / 256, 256, 0, stream>>>(
        (const int4*)idx, idx, starts, n4, n, S);
    if (n % 4) {
        build_starts_tail<<<((n - n4 * 4) + 255) / 256, 256, 0, stream>>>(
            idx, starts, n4, n, S);
    }

    if (d == 128 && (S % 2) == 0) {
        seg_weighted_avg_d128<<<S / 2, 128, 0, stream>>>(
            (const f32x4*)prop, w, starts, (f32x4*)out);
    } else {
        seg_weighted_avg_generic<<<S, d, 0, stream>>>(prop, w, starts, out, d);
    }
}